// Round 1
// baseline (57.296 us; speedup 1.0000x reference)
//
#include <hip/hip_runtime.h>

// Problem constants (match reference)
#define NG   48
#define NG2  (NG * NG)
#define NG3  (NG * NG * NG)
#define N_ATOMS 1024

// r^2 computed exactly as the numpy/JAX reference does:
// double (1.5*1.52) -> squared in double -> cast fp32
__device__ __forceinline__ float radius2_f32() {
    const double rd = 1.5 * 1.52;
    return (float)(rd * rd);
}

// Kernel 1: initialize output to the "uncovered" state: ch0 = 0, ch1 = 1.
// 2*NG3 = 221184 floats = 55296 float4. NG3/4 = 27648 zero-float4s first.
__global__ void wat_init_out(float* __restrict__ out) {
    int i = blockIdx.x * blockDim.x + threadIdx.x;
    const int n4 = (2 * NG3) / 4;          // 55296
    if (i < n4) {
        float v = (i < NG3 / 4) ? 0.0f : 1.0f;
        reinterpret_cast<float4*>(out)[i] = make_float4(v, v, v, v);
    }
}

// Kernel 2: atom-centric scatter. One block per atom; threads sweep the
// atom's voxel bounding box and mark covered voxels. Writes are idempotent
// (all writers store identical values), so plain stores are race-safe.
__global__ void wat_scatter(const float* __restrict__ vecs,
                            float* __restrict__ out) {
    const int a = blockIdx.x;
    // All threads read the same 3 floats -> broadcast via cache, cheap.
    const float ax = vecs[3 * a + 0];
    const float ay = vecs[3 * a + 1];
    const float az = vecs[3 * a + 2];

    const float R2 = radius2_f32();
    const float Rc = 2.2805f;              // slightly conservative radius bound

    // Conservative voxel index bounds per axis (exact test inside loop).
    // voxel coord = 0.5*i  ->  i = 2*coord
    int x0 = max(0,      (int)floorf((ax - Rc) * 2.0f));
    int x1 = min(NG - 1, (int)ceilf ((ax + Rc) * 2.0f));
    int y0 = max(0,      (int)floorf((ay - Rc) * 2.0f));
    int y1 = min(NG - 1, (int)ceilf ((ay + Rc) * 2.0f));
    int z0 = max(0,      (int)floorf((az - Rc) * 2.0f));
    int z1 = min(NG - 1, (int)ceilf ((az + Rc) * 2.0f));

    const int nx = x1 - x0 + 1;
    const int ny = y1 - y0 + 1;
    const int nz = z1 - z0 + 1;
    const int total = nx * ny * nz;        // <= ~1331

    for (int t = threadIdx.x; t < total; t += blockDim.x) {
        const int iz  = z0 + (t % nz);
        const int rem = t / nz;
        const int iy  = y0 + (rem % ny);
        const int ix  = x0 + (rem / ny);

        // Bit-exact replication of reference fp32 arithmetic:
        // d2 = (dx^2 + dy^2) + dz^2, dx = atom - voxel, voxel = 0.5*i (exact)
        const float dx = __fsub_rn(ax, 0.5f * (float)ix);
        const float dy = __fsub_rn(ay, 0.5f * (float)iy);
        const float dz = __fsub_rn(az, 0.5f * (float)iz);
        const float d2 = __fadd_rn(__fadd_rn(__fmul_rn(dx, dx),
                                             __fmul_rn(dy, dy)),
                                   __fmul_rn(dz, dz));
        if (d2 < R2) {
            const int idx = ix * NG2 + iy * NG + iz;
            out[idx]       = 1.0f;          // ch0: covered -> 1
            out[NG3 + idx] = 25.0f;         // ch1: covered -> WEIGHT
        }
    }
}

extern "C" void kernel_launch(void* const* d_in, const int* in_sizes, int n_in,
                              void* d_out, int out_size, void* d_ws, size_t ws_size,
                              hipStream_t stream) {
    const float* vecs = (const float*)d_in[0];
    float* out = (float*)d_out;

    // 55296 float4 elements / 256 threads = 216 blocks
    wat_init_out<<<216, 256, 0, stream>>>(out);
    // one block per atom
    wat_scatter<<<N_ATOMS, 256, 0, stream>>>(vecs, out);
}